// Round 20
// baseline (226.795 us; speedup 1.0000x reference)
//
#include <hip/hip_runtime.h>
#include <hip/hip_bf16.h>
#include <math.h>

#define H_ 16
#define DK_ 128
#define DV_ 128
#define D_ 2048
#define T_ 256
#define B_ 2
#define BT_ 512

typedef __attribute__((ext_vector_type(8))) short short8v;
typedef __attribute__((ext_vector_type(4))) float float4v;
typedef unsigned short ushort_t;

__device__ __forceinline__ float sigmoidf_(float x){ return 1.f/(1.f+expf(-x)); }
__device__ __forceinline__ float siluf_(float x){ return x/(1.f+expf(-x)); }
__device__ __forceinline__ ushort_t f2bf(float f){
    __hip_bfloat16 h = __float2bfloat16(f);
    return *reinterpret_cast<ushort_t*>(&h);
}
// swizzled LDS index (shorts) for N-row x 32-col bf16 tiles; k multiple of 8 in use
__device__ __forceinline__ int swz(int row, int k){
    return row * 32 + ((((k >> 3) ^ (row & 3)) << 3) | (k & 7));
}

// DPP row-rotation sum over a 16-lane row (pure VALU, no LDS pipe).
template<int CTRL>
__device__ __forceinline__ float ror_add_(float x){
    return x + __int_as_float(__builtin_amdgcn_update_dpp(
        0, __float_as_int(x), CTRL, 0xF, 0xF, true));
}
__device__ __forceinline__ float rsum16_(float x){
    x = ror_add_<0x121>(x);
    x = ror_add_<0x122>(x);
    x = ror_add_<0x124>(x);
    x = ror_add_<0x128>(x);
    return x;
}

// ---------------- fused fp32->bf16 + gchan precompute ----------------
__global__ void cvt_gchan(const float* __restrict__ in, ushort_t* __restrict__ out, int n,
                          const float* __restrict__ A_log, const float* __restrict__ dt_bias,
                          float* __restrict__ gchan)
{
    int bid = blockIdx.x;
    if (bid < 1024) {
        int i = (bid * 256 + threadIdx.x) * 4;
        if (i >= n) return;
        float4 v = *(const float4*)&in[i];
        union { ushort_t s[4]; unsigned long long u; } p;
        p.s[0] = f2bf(v.x); p.s[1] = f2bf(v.y); p.s[2] = f2bf(v.z); p.s[3] = f2bf(v.w);
        *(unsigned long long*)&out[i] = p.u;
    } else {
        int i = (bid - 1024) * 256 + threadIdx.x;   // 0..2047
        int h = i >> 7;
        float x = dt_bias[i];
        float sp = (x > 20.f) ? x : log1pf(expf(x));
        gchan[i] = -expf(A_log[h]) * sp * 1.44269504088896f;
    }
}

// ---------------- GEMM core (64-row tiles, 256 thr): proven, for small GEMMs -------
__device__ __forceinline__ void gemm_core(
    const ushort_t* __restrict__ A, int K,
    const float* __restrict__ W, int Nst, int nloc0,
    float* __restrict__ C, int Cst, int m0, int n0out)
{
    __shared__ ushort_t Asub[2048];
    __shared__ ushort_t Bsub[2048];
    const int tid = threadIdx.x;
    const int wid = tid >> 6, lane = tid & 63;
    const int wr = (wid >> 1) * 32, wc = (wid & 1) * 32;
    const int lr = lane & 15, lk = (lane >> 4) * 8;
    const int rowA = tid >> 2, kqA = tid & 3;
    const int nW = tid & 63, kqW = tid >> 6;

    float4v acc[2][2];
    #pragma unroll
    for (int i = 0; i < 2; ++i)
        #pragma unroll
        for (int j = 0; j < 2; ++j) acc[i][j] = (float4v){0.f, 0.f, 0.f, 0.f};

    short8v aRa, aRb;
    float wRa[8], wRb[8];

#define LOADT(AR, WR, KOFF) do {                                                   \
    AR = *(const short8v*)&A[(size_t)(m0 + rowA) * K + (KOFF) + kqA * 8];          \
    _Pragma("unroll")                                                              \
    for (int r = 0; r < 8; ++r)                                                    \
        WR[r] = W[(size_t)((KOFF) + kqW * 8 + r) * Nst + nloc0 + nW];              \
} while (0)
#define STORET(AR, WR) do {                                                        \
    *(short8v*)&Asub[swz(rowA, kqA * 8)] = AR;                                     \
    union { ushort_t s[8]; short8v v; } pk;                                        \
    _Pragma("unroll")                                                              \
    for (int r = 0; r < 8; ++r) pk.s[r] = f2bf(WR[r]);                             \
    *(short8v*)&Bsub[swz(nW, kqW * 8)] = pk.v;                                     \
} while (0)
#define FRAGMMA() do {                                                             \
    short8v af0 = *(const short8v*)&Asub[swz(wr + lr, lk)];                        \
    short8v af1 = *(const short8v*)&Asub[swz(wr + 16 + lr, lk)];                   \
    short8v bf0 = *(const short8v*)&Bsub[swz(wc + lr, lk)];                        \
    short8v bf1 = *(const short8v*)&Bsub[swz(wc + 16 + lr, lk)];                   \
    acc[0][0] = __builtin_amdgcn_mfma_f32_16x16x32_bf16(af0, bf0, acc[0][0],0,0,0);\
    acc[0][1] = __builtin_amdgcn_mfma_f32_16x16x32_bf16(af0, bf1, acc[0][1],0,0,0);\
    acc[1][0] = __builtin_amdgcn_mfma_f32_16x16x32_bf16(af1, bf0, acc[1][0],0,0,0);\
    acc[1][1] = __builtin_amdgcn_mfma_f32_16x16x32_bf16(af1, bf1, acc[1][1],0,0,0);\
} while (0)

    LOADT(aRa, wRa, 0);
    for (int k0 = 0; k0 < K; k0 += 64) {
        STORET(aRa, wRa);
        __syncthreads();
        if (k0 + 32 < K) LOADT(aRb, wRb, k0 + 32);
        FRAGMMA();
        __syncthreads();
        STORET(aRb, wRb);
        __syncthreads();
        if (k0 + 64 < K) LOADT(aRa, wRa, k0 + 64);
        FRAGMMA();
        __syncthreads();
    }
#undef LOADT
#undef STORET
#undef FRAGMMA
    const int lq = (lane >> 4) * 4;
    #pragma unroll
    for (int mi = 0; mi < 2; ++mi)
        #pragma unroll
        for (int ni = 0; ni < 2; ++ni)
            #pragma unroll
            for (int j = 0; j < 4; ++j)
                C[(size_t)(m0 + wr + mi * 16 + lq + j) * Cst + (n0out + wc + ni * 16 + lr)]
                    = acc[mi][ni][j];
}

// ---------------- GEMM core2 (256-row tiles, 512 thr) ----------
__device__ __forceinline__ void gemm_core2(
    const ushort_t* __restrict__ A, int K,
    const float* __restrict__ W, int Nst, int nloc0,
    float* __restrict__ C, int Cst, int m0, int n0out)
{
    __shared__ ushort_t Asub[8192];   // 256 x 32, swizzled
    __shared__ ushort_t Bsub[2048];   // 64 x 32, swizzled
    const int tid = threadIdx.x;      // 0..511
    const int wid = tid >> 6, lane = tid & 63;
    const int wr = wid * 32;
    const int lr = lane & 15, lk = (lane >> 4) * 8;
    const int rowA = tid >> 2;
    const int kqA  = (tid & 3) * 8;
    const int nW = tid & 63, kqW = (tid >> 6) & 3;
    const bool doW = tid < 256;

    float4v acc[2][4];
    #pragma unroll
    for (int i = 0; i < 2; ++i)
        #pragma unroll
        for (int j = 0; j < 4; ++j) acc[i][j] = (float4v){0.f, 0.f, 0.f, 0.f};

    short8v a0a, a1a, a0b, a1b;
    float wRa[8], wRb[8];

#define LOADT2(A0, A1, WR, KOFF) do {                                              \
    A0 = *(const short8v*)&A[(size_t)(m0 + rowA) * K + (KOFF) + kqA];              \
    A1 = *(const short8v*)&A[(size_t)(m0 + rowA + 128) * K + (KOFF) + kqA];        \
    if (doW) {                                                                     \
        _Pragma("unroll")                                                          \
        for (int r = 0; r < 8; ++r)                                                \
            WR[r] = W[(size_t)((KOFF) + kqW * 8 + r) * Nst + nloc0 + nW];          \
    }                                                                              \
} while (0)
#define STORET2(A0, A1, WR) do {                                                   \
    *(short8v*)&Asub[swz(rowA, kqA)] = A0;                                         \
    *(short8v*)&Asub[swz(rowA + 128, kqA)] = A1;                                   \
    if (doW) {                                                                     \
        union { ushort_t s[8]; short8v v; } pk;                                    \
        _Pragma("unroll")                                                          \
        for (int r = 0; r < 8; ++r) pk.s[r] = f2bf(WR[r]);                         \
        *(short8v*)&Bsub[swz(nW, kqW * 8)] = pk.v;                                 \
    }                                                                              \
} while (0)
#define FRAGMMA2() do {                                                            \
    short8v af0 = *(const short8v*)&Asub[swz(wr + lr, lk)];                        \
    short8v af1 = *(const short8v*)&Asub[swz(wr + 16 + lr, lk)];                   \
    short8v bf0 = *(const short8v*)&Bsub[swz(lr, lk)];                             \
    short8v bf1 = *(const short8v*)&Bsub[swz(16 + lr, lk)];                        \
    short8v bf2 = *(const short8v*)&Bsub[swz(32 + lr, lk)];                        \
    short8v bf3 = *(const short8v*)&Bsub[swz(48 + lr, lk)];                        \
    acc[0][0] = __builtin_amdgcn_mfma_f32_16x16x32_bf16(af0, bf0, acc[0][0],0,0,0);\
    acc[0][1] = __builtin_amdgcn_mfma_f32_16x16x32_bf16(af0, bf1, acc[0][1],0,0,0);\
    acc[0][2] = __builtin_amdgcn_mfma_f32_16x16x32_bf16(af0, bf2, acc[0][2],0,0,0);\
    acc[0][3] = __builtin_amdgcn_mfma_f32_16x16x32_bf16(af0, bf3, acc[0][3],0,0,0);\
    acc[1][0] = __builtin_amdgcn_mfma_f32_16x16x32_bf16(af1, bf0, acc[1][0],0,0,0);\
    acc[1][1] = __builtin_amdgcn_mfma_f32_16x16x32_bf16(af1, bf1, acc[1][1],0,0,0);\
    acc[1][2] = __builtin_amdgcn_mfma_f32_16x16x32_bf16(af1, bf2, acc[1][2],0,0,0);\
    acc[1][3] = __builtin_amdgcn_mfma_f32_16x16x32_bf16(af1, bf3, acc[1][3],0,0,0);\
} while (0)

    LOADT2(a0a, a1a, wRa, 0);
    for (int k0 = 0; k0 < K; k0 += 64) {
        STORET2(a0a, a1a, wRa);
        __syncthreads();
        if (k0 + 32 < K) LOADT2(a0b, a1b, wRb, k0 + 32);
        FRAGMMA2();
        __syncthreads();
        STORET2(a0b, a1b, wRb);
        __syncthreads();
        if (k0 + 64 < K) LOADT2(a0a, a1a, wRa, k0 + 64);
        FRAGMMA2();
        __syncthreads();
    }
#undef LOADT2
#undef STORET2
#undef FRAGMMA2
    const int lq = (lane >> 4) * 4;
    #pragma unroll
    for (int mi = 0; mi < 2; ++mi)
        #pragma unroll
        for (int ni = 0; ni < 4; ++ni)
            #pragma unroll
            for (int j = 0; j < 4; ++j)
                C[(size_t)(m0 + wr + mi * 16 + lq + j) * Cst + (n0out + ni * 16 + lr)]
                    = acc[mi][ni][j];
}

// fused projection GEMM: N = 6336 = wq(2048) | wk(2048) | wv(2048) | unc(64) | g1(128)
__global__ __launch_bounds__(512) void gemm_proj(const ushort_t* __restrict__ A,
    const float* __restrict__ wq, const float* __restrict__ wk, const float* __restrict__ wv,
    const float* __restrict__ unc, const float* __restrict__ g1, float* __restrict__ C)
{
    int n0 = blockIdx.x * 64, m0 = blockIdx.y * 256;
    const float* W; int nloc, Nst;
    if (n0 < 2048)      { W = wq;  nloc = n0;        Nst = 2048; }
    else if (n0 < 4096) { W = wk;  nloc = n0 - 2048; Nst = 2048; }
    else if (n0 < 6144) { W = wv;  nloc = n0 - 4096; Nst = 2048; }
    else if (n0 < 6208) { W = unc; nloc = n0 - 6144; Nst = 64; }
    else                { W = g1;  nloc = n0 - 6208; Nst = 128; }
    gemm_core2(A, 2048, W, Nst, nloc, C, 6336, m0, n0);
}

// single-weight GEMM (64-tile): C[M,N] = A[M,K] @ W[K,N]
__global__ __launch_bounds__(256) void gemm_one(const ushort_t* __restrict__ A,
    const float* __restrict__ W, float* __restrict__ C, int N, int K)
{
    gemm_core(A, K, W, N, blockIdx.x * 64, C, N, blockIdx.y * 64, blockIdx.x * 64);
}

// ---------------- fused causal depthwise conv (K=4) + SiLU over q|k|v --------------
__global__ void conv_fused(const float* __restrict__ Cb,
    const float* __restrict__ wq, const float* __restrict__ wk, const float* __restrict__ wv,
    float* __restrict__ qc, float* __restrict__ kc, float* __restrict__ vc,
    ushort_t* __restrict__ kcb, float qscale)
{
    int c  = blockIdx.x * 256 + threadIdx.x;   // 0..6143
    int bt = blockIdx.y;
    int b  = bt / T_, t = bt % T_;
    int which = c >> 11, cloc = c & 2047;
    const float* w = which == 0 ? wq : which == 1 ? wk : wv;
    float* o = which == 0 ? qc : which == 1 ? kc : vc;
    float scale = which == 0 ? qscale : 1.f;
    float acc = 0.f;
    #pragma unroll
    for (int j = 0; j < 4; ++j) {
        int tt = t - 3 + j;
        if (tt >= 0) acc = fmaf(w[cloc * 4 + j], Cb[((size_t)(b * T_ + tt)) * 6336 + c], acc);
    }
    float r = siluf_(acc) * scale;
    o[(size_t)bt * D_ + cloc] = r;
    if (which == 1) kcb[(size_t)bt * D_ + cloc] = f2bf(r);
}

// ---------- fused per-(b,t,h) features + MLP + scan-operand precompute -------------
__global__ __launch_bounds__(128) void featsprec_k(
    const float* __restrict__ kc, const float* __restrict__ vc,
    const float* __restrict__ qc,
    const float* __restrict__ vhatA, const float* __restrict__ Cb,
    const float* __restrict__ he, const float* __restrict__ gchan,
    const float* __restrict__ w1, const float* __restrict__ b1,
    const float* __restrict__ w2, const float* __restrict__ b2,
    const float* __restrict__ bbw, const float* __restrict__ bbb,
    const float* __restrict__ bdw, const float* __restrict__ bdb,
    const float* __restrict__ lamw, const float* __restrict__ lamb,
    const float* __restrict__ abw, const float* __restrict__ abb,
    const float* __restrict__ adw, const float* __restrict__ adb,
    float* __restrict__ lm, float* __restrict__ kuA,
    float* __restrict__ dA, float4* __restrict__ scal4A)
{
    int blk = blockIdx.x;          // (b*T+t)*H + h
    int h = blk & 15, bt = blk >> 4;
    int b = bt / T_, t = bt % T_;
    int v = threadIdx.x;           // 0..127
    __shared__ float part[2][5];
    __shared__ float tot5[5];
    __shared__ float feats8[8];
    __shared__ float hf1[32];
    __shared__ float hf[32];
    __shared__ float entSh;
    __shared__ float scal5[5];     // bfv, bsv, afv, asv, knorm

    if (v < 64) {
        float x = Cb[(size_t)bt * 6336 + 6144 + v];
        float m = x;
        #pragma unroll
        for (int o = 32; o > 0; o >>= 1) m = fmaxf(m, __shfl_xor(m, o));
        float e = expf(x - m);
        float s = e;
        #pragma unroll
        for (int o = 32; o > 0; o >>= 1) s += __shfl_xor(s, o);
        float lp = (x - m) - logf(s);
        float c = -expf(lp) * lp;
        #pragma unroll
        for (int o = 32; o > 0; o >>= 1) c += __shfl_xor(c, o);
        if (v == 0) entSh = c / logf(64.f);
    }

    size_t base = (size_t)bt * D_ + h * 128;
    float kval = kc[base + v];
    float vval = vc[base + v];
    float vhat = vhatA[(size_t)blk * 128 + v];

    float e = vval - vhat;
    float sums[5] = {kval * kval, vval * vval, vhat * vhat, vval * vhat, e * e};
    #pragma unroll
    for (int i = 0; i < 5; ++i) {
        float s = sums[i];
        #pragma unroll
        for (int o = 32; o > 0; o >>= 1) s += __shfl_xor(s, o);
        if ((threadIdx.x & 63) == 0) part[threadIdx.x >> 6][i] = s;
    }
    __syncthreads();
    if (threadIdx.x < 5) tot5[threadIdx.x] = part[0][threadIdx.x] + part[1][threadIdx.x];
    __syncthreads();
    if (threadIdx.x == 0) {
        float k2 = tot5[0], v2 = tot5[1], vh2 = tot5[2], vvh = tot5[3], e2 = tot5[4];
        float knorm = sqrtf(k2);
        float err_n = sqrtf(e2);
        float v_n = sqrtf(v2);
        float vh_n = sqrtf(vh2);
        feats8[0] = entSh;
        feats8[1] = err_n / (v_n + 1e-6f);
        feats8[2] = vvh / (v_n * vh_n + 1e-6f);
        feats8[3] = log1pf(err_n);
        feats8[4] = he[h * 4 + 0];
        feats8[5] = he[h * 4 + 1];
        feats8[6] = he[h * 4 + 2];
        feats8[7] = he[h * 4 + 3];
        scal5[4] = knorm;
    }
    __syncthreads();
    if (threadIdx.x < 32) {
        float a = b1[threadIdx.x];
        #pragma unroll
        for (int j = 0; j < 8; ++j) a = fmaf(feats8[j], w1[j * 32 + threadIdx.x], a);
        hf1[threadIdx.x] = siluf_(a);
    }
    __syncthreads();
    if (threadIdx.x < 32) {
        float a = b2[threadIdx.x];
        #pragma unroll
        for (int j = 0; j < 32; ++j) a = fmaf(hf1[j], w2[j * 32 + threadIdx.x], a);
        hf[threadIdx.x] = siluf_(a);
    }
    __syncthreads();
    if (threadIdx.x == 0) {
        float bb = bbb[0], bd = bdb[0], lv = lamb[0], ab = abb[0], ad = adb[0];
        #pragma unroll
        for (int j = 0; j < 32; ++j) {
            float hj = hf[j];
            bb = fmaf(hj, bbw[j], bb);
            bd = fmaf(hj, bdw[j], bd);
            lv = fmaf(hj, lamw[j], lv);
            ab = fmaf(hj, abw[j], ab);
            ad = fmaf(hj, adw[j], ad);
        }
        scal5[0] = sigmoidf_(bb + bd);
        scal5[1] = sigmoidf_(bb - bd);
        scal5[2] = sigmoidf_(ab + ad);
        scal5[3] = sigmoidf_(ab - ad);
        lm[((size_t)(b * H_ + h)) * T_ + t] = sigmoidf_(lv);
    }
    __syncthreads();

    // ---- scan-operand precompute (reads precomputed gchan) ----
    const float bfv = scal5[0], bsv = scal5[1];
    const float afv = scal5[2], asv = scal5[3], knv = scal5[4];
    const int k = threadIdx.x;
    const int bh = b * 16 + h;
    float gch = gchan[h * 128 + k];
    float kuv = kval / (knv + 1e-6f);
    kuA[((size_t)bh * 256 + t) * 128 + k] = kuv;
    dA[((size_t)bh * 256 + t) * 128 + k]        = exp2f(gch * afv);   // rule 0
    dA[((size_t)(32 + bh) * 256 + t) * 128 + k] = exp2f(gch * asv);   // rule 1
    float pq = qc[base + k] * kuv;
    #pragma unroll
    for (int o = 32; o > 0; o >>= 1) pq += __shfl_xor(pq, o);
    if ((threadIdx.x & 63) == 0) part[threadIdx.x >> 6][0] = pq;
    __syncthreads();
    if (threadIdx.x == 0) {
        float pt = part[0][0] + part[1][0];
        float4 s0; s0.x = afv; s0.y = bfv; s0.z = pt * bfv; s0.w = 0.f;
        float4 s1; s1.x = asv; s1.y = bsv; s1.z = pt * bsv; s1.w = 0.f;
        scal4A[(size_t)bh * 256 + t] = s0;
        scal4A[(size_t)(32 + bh) * 256 + t] = s1;
    }
}

// ------ fused delta-rule scan (blocks 0..511, 2/CU) + g2 GEMM (blocks 512..767) ----
// v-split x8: block covers 16 v-cols; lane owns S[8k][1v]; second block per CU
// hides the ~200cyc dependent chain. g2 tail-fills after scan residency.
struct OPS { float4 a0, a1, q0, q1, d0, d1; float2 sc2; float vv; };

__global__ __launch_bounds__(256) void delta_g2_fused(
    const float* __restrict__ qc, const float* __restrict__ vc,
    const float* __restrict__ kuA, const float* __restrict__ dA,
    const float4* __restrict__ scal4A,
    float* __restrict__ o_fast, float* __restrict__ o_slow,
    const float* __restrict__ Cb, const float* __restrict__ g2w,
    float* __restrict__ graw)
{
    __shared__ __align__(16) char smem[57600];
    const int tid = threadIdx.x;

    if (blockIdx.x >= 512) {
        // ---------------- g2 GEMM path: graw = Cb[:,6208:6336] @ g2w ----------------
        ushort_t* Asub = (ushort_t*)smem;            // 2048 shorts
        ushort_t* Bsub = (ushort_t*)(smem + 4096);   // 2048 shorts
        const int p2 = blockIdx.x - 512;             // 0..255
        const int m0 = (p2 >> 5) * 64, n0 = (p2 & 31) * 64;
        const int wid = tid >> 6, lane = tid & 63;
        const int wr = (wid >> 1) * 32, wc = (wid & 1) * 32;
        const int lr = lane & 15, lk = (lane >> 4) * 8;
        const int rowA = tid >> 2, kqA = (tid & 3) * 8;
        const int nW = tid & 63, kqW = tid >> 6;

        float4v acc[2][2];
        #pragma unroll
        for (int i = 0; i < 2; ++i)
            #pragma unroll
            for (int j = 0; j < 2; ++j) acc[i][j] = (float4v){0.f, 0.f, 0.f, 0.f};

        for (int k0 = 0; k0 < 128; k0 += 32) {
            const float* asrc = &Cb[(size_t)(m0 + rowA) * 6336 + 6208 + k0 + kqA];
            float4 a4a = *(const float4*)asrc;
            float4 a4b = *(const float4*)(asrc + 4);
            float w8[8];
            #pragma unroll
            for (int r = 0; r < 8; ++r)
                w8[r] = g2w[(size_t)(k0 + kqW * 8 + r) * 2048 + n0 + nW];
            __syncthreads();
            union { ushort_t s[8]; short8v v; } pa, pw;
            pa.s[0]=f2bf(a4a.x); pa.s[1]=f2bf(a4a.y); pa.s[2]=f2bf(a4a.z); pa.s[3]=f2bf(a4a.w);
            pa.s[4]=f2bf(a4b.x); pa.s[5]=f2bf(a4b.y); pa.s[6]=f2bf(a4b.z); pa.s[7]=f2bf(a4b.w);
            *(short8v*)&Asub[swz(rowA, kqA)] = pa.v;
            #pragma unroll
            for (int r = 0; r < 8; ++r) pw.s[r] = f2bf(w8[r]);
            *(short8v*)&Bsub[swz(nW, kqW * 8)] = pw.v;
            __syncthreads();
            short8v af0 = *(const short8v*)&Asub[swz(wr + lr, lk)];
            short8v af1 = *(const short8v*)&Asub[swz(wr + 16 + lr, lk)];
            short8v bf0 = *(const short8v*)&Bsub[swz(wc + lr, lk)];
            short8v bf1 = *(const short8v*)&Bsub[swz(wc + 16 + lr, lk)];
            acc[0][0] = __builtin_amdgcn_mfma_f32_16x16x32_bf16(af0, bf0, acc[0][0],0,0,0);
            acc[0][1] = __builtin_amdgcn_mfma_f32_16x16x32_bf16(af0, bf1, acc[0][1],0,0,0);
            acc[1][0] = __builtin_amdgcn_mfma_f32_16x16x32_bf16(af1, bf0, acc[1][0],0,0,0);
            acc[1][1] = __builtin_amdgcn_mfma_f32_16x16x32_bf16(af1, bf1, acc[1][1],0,0,0);
        }
        const int lq = (lane >> 4) * 4;
        #pragma unroll
        for (int mi = 0; mi < 2; ++mi)
            #pragma unroll
            for (int ni = 0; ni < 2; ++ni)
                #pragma unroll
                for (int j = 0; j < 4; ++j)
                    graw[(size_t)(m0 + wr + mi * 16 + lq + j) * 2048 + (n0 + wc + ni * 16 + lr)]
                        = acc[mi][ni][j];
        return;
    }

    // ---------------- scan path: v-split x8, lane owns S[8k][1v] ----------------
    float (*kuL)[16][144] = (float (*)[16][144])(smem);            // 18432 B
    float (*qL)[16][144]  = (float (*)[16][144])(smem + 18432);    // 18432 B
    float (*dL)[16][144]  = (float (*)[16][144])(smem + 36864);    // 18432 B
    float (*vL)[16][16]   = (float (*)[16][16])(smem + 55296);     //  2048 B
    float (*scL)[16][2]   = (float (*)[16][2])(smem + 57344);      //   256 B

    const int p  = blockIdx.x;                    // 0..511 ; XCD = p & 7
    const int lb = (p & 7) * 64 + (p >> 3);       // bh*16 + rule*8 + vq
    const int bh = lb >> 4, rule = (lb >> 3) & 1, vq = lb & 7;
    const int b = bh >> 4, h = bh & 15;
    const int rbh = rule * 32 + bh;
    const int wid = tid >> 6, lane = tid & 63;
    const int kl = lane & 15, vg = lane >> 4;
    const int vloc = wid * 4 + vg;                // 0..15 within 16-col slice
    const int vcol = vq * 16 + vloc;

    const float*  __restrict__ pkuG = kuA + (size_t)bh * 256 * 128;
    const float*  __restrict__ pdG  = dA + (size_t)rbh * 256 * 128;
    const float*  __restrict__ pqG  = qc + (size_t)b * T_ * D_ + h * 128;
    const float*  __restrict__ pvG  = vc + (size_t)b * T_ * D_ + h * 128 + vq * 16;
    const float4* __restrict__ pscG = scal4A + (size_t)rbh * 256;
    float* __restrict__ obase = (rule ? o_slow : o_fast)
                                + (size_t)b * T_ * D_ + h * 128 + vcol;

    const int srow = (tid & 127) >> 3;            // 0..15
    const int scol = (tid & 7) * 16;              // 0..112
    const bool isK = tid < 128;
    const int ck0 = scol >> 3;                    // 8-float group index (even)
    const int fo_w0 = ck0 * 8 + (ck0 >> 2) * 4;
    const int fo_w1 = (ck0 + 1) * 8 + ((ck0 + 1) >> 2) * 4;

    float4 sb0, sb1, sb2, sb3, svb, ssc, sd0, sd1;

    float S[8];
    #pragma unroll
    for (int j = 0; j < 8; ++j) S[j] = 0.f;

#define STAGE_LOAD(C) do {                                                         \
    const int t0_ = (C) * 16;                                                      \
    const float* dsrc = pdG + (size_t)(t0_ + srow) * 128 + scol;                   \
    if (isK) {                                                                     \
        const float* src = pkuG + (size_t)(t0_ + srow) * 128 + scol;               \
        sb0 = *(const float4*)(src);      sb1 = *(const float4*)(src + 4);         \
        sb2 = *(const float4*)(src + 8);  sb3 = *(const float4*)(src + 12);        \
        if ((tid & 7) < 4)                                                         \
            svb = *(const float4*)(pvG + (size_t)(t0_ + srow) * D_ + (tid & 3) * 4);\
        sd0 = *(const float4*)(dsrc);     sd1 = *(const float4*)(dsrc + 4);        \
    } else {                                                                       \
        const float* src = pqG + (size_t)(t0_ + srow) * D_ + scol;                 \
        sb0 = *(const float4*)(src);      sb1 = *(const float4*)(src + 4);         \
        sb2 = *(const float4*)(src + 8);  sb3 = *(const float4*)(src + 12);        \
        sd0 = *(const float4*)(dsrc + 8); sd1 = *(const float4*)(dsrc + 12);       \
        if ((tid & 127) < 16) ssc = *(const float4*)&pscG[t0_ + (tid & 127)];      \
    }                                                                              \
} while (0)

#define STAGE_WRITE(BI) do {                                                       \
    if (isK) {                                                                     \
        *(float4*)&kuL[BI][srow][fo_w0]     = sb0;                                 \
        *(float4*)&kuL[BI][srow][fo_w0 + 4] = sb1;                                 \
        *(float4*)&kuL[BI][srow][fo_w1]     = sb2;                                 \
        *(float4*)&kuL[BI][srow][fo_w1 + 4] = sb3;                                 \
        if ((tid & 7) < 4) *(float4*)&vL[BI][srow][(tid & 3) * 4] = svb;           \
        *(float4*)&dL[BI][srow][fo_w0]      = sd0;                                 \
        *(float4*)&dL[BI][srow][fo_w0 + 4]  = sd1;                                 \
    } else {                                                                       \
        *(float4*)&qL[BI][srow][fo_w0]     = sb0;                                  \
        *(float4*)&qL[BI][srow][fo_w0 + 4] = sb1;                                  \
        *(float4*)&qL[BI][srow][fo_w1]     = sb2;                                  \
        *(float4*)&qL[BI][srow][fo_w1 + 4] = sb3;                                  \
        *(float4*)&dL[BI][srow][fo_w1]      = sd0;                                 \
        *(float4*)&dL[BI][srow][fo_w1 + 4]  = sd1;                                 \
        if ((tid & 127) < 16) {                                                    \
            float2 w2_; w2_.x = ssc.y; w2_.y = ssc.z;                              \
            *(float2*)&scL[BI][tid & 127][0] = w2_;                                \
        }                                                                          \
    }                                                                              \
} while (0)

#define LDOPS(R, BI, TS) do {                                                      \
    R.a0 = *(const float4*)&kuL[BI][TS][fo];                                       \
    R.a1 = *(const float4*)&kuL[BI][TS][fo + 4];                                   \
    R.q0 = *(const float4*)&qL[BI][TS][fo];                                        \
    R.q1 = *(const float4*)&qL[BI][TS][fo + 4];                                    \
    R.d0 = *(const float4*)&dL[BI][TS][fo];                                        \
    R.d1 = *(const float4*)&dL[BI][TS][fo + 4];                                    \
    R.vv = vL[BI][TS][vloc];                                                       \
    R.sc2 = *(const float2*)&scL[BI][TS][0];                                       \
} while (0)

#define STEP(TT, CUR, NXT, BI) do {                                                \
    if ((TT) + 1 < 16) LDOPS(NXT, BI, (TT) + 1);                                   \
    float ku[8] = {CUR.a0.x, CUR.a0.y, CUR.a0.z, CUR.a0.w,                         \
                   CUR.a1.x, CUR.a1.y, CUR.a1.z, CUR.a1.w};                        \
    float qv[8] = {CUR.q0.x, CUR.q0.y, CUR.q0.z, CUR.q0.w,                         \
                   CUR.q1.x, CUR.q1.y, CUR.q1.z, CUR.q1.w};                        \
    float d[8]  = {CUR.d0.x, CUR.d0.y, CUR.d0.z, CUR.d0.w,                         \
                   CUR.d1.x, CUR.d1.y, CUR.d1.z, CUR.d1.w};                        \
    float vpa = 0.f, vpb = 0.f, oqa = 0.f, oqb = 0.f;                              \
    _Pragma("unroll")                                                              \
    for (int j = 0; j < 4; ++j) {                                                  \
        float kudA = ku[j] * d[j],     qdA = qv[j] * d[j];                         \
        float kudB = ku[j+4] * d[j+4], qdB = qv[j+4] * d[j+4];                     \
        vpa = fmaf(kudA, S[j], vpa);   vpb = fmaf(kudB, S[j+4], vpb);              \
        oqa = fmaf(qdA,  S[j], oqa);   oqb = fmaf(qdB,  S[j+4], oqb);              \
    }                                                                              \
    float vp = rsum16_(vpa + vpb);                                                 \
    float oq = rsum16_(oqa + oqb);                                                 \
    float dv = CUR.vv - vp;                                                        \
    float o = fmaf(CUR.sc2.y, dv, oq);                                             \
    float bd = CUR.sc2.x * dv;                                                     \
    _Pragma("unroll")                                                              \
    for (int j = 0; j < 8; ++j)                                                    \
        S[j] = fmaf(d[j], S[j], ku[j] * bd);                                       \
    if (kl == 0) obase[(size_t)(tb + (TT)) * D_] = o;                              \
} while (0)

    const int fo = kl * 8 + (kl >> 2) * 4;

    STAGE_LOAD(0);
    STAGE_WRITE(0);
    __syncthreads();

    OPS rA, rB;
    for (int c = 0; c < 16; ++c) {
        if (c < 15) STAGE_LOAD(c + 1);
        const int bi = c & 1;
        const int tb = c * 16;
        LDOPS(rA, bi, 0);
        #pragma unroll
        for (int ts = 0; ts < 16; ts += 2) {
            STEP(ts,     rA, rB, bi);
            STEP(ts + 1, rB, rA, bi);
        }
        if (c < 15) STAGE_WRITE((c + 1) & 1);
        __syncthreads();
    }
#undef STAGE_LOAD
#undef STAGE_WRITE
#undef LDOPS
#undef STEP
}

// ---------------- combine fast/slow + RMSNorm + sigmoid gate -> bf16 ----------------
__global__ __launch_bounds__(128) void combine_k(
    const float* __restrict__ of, const float* __restrict__ os,
    const float* __restrict__ lm, const float* __restrict__ graw,
    const float* __restrict__ g2b, const float* __restrict__ onw,
    ushort_t* __restrict__ ocb)
{
    int blk = blockIdx.x;          // (b*T+t)*H + h
    int h = blk & 15, bt = blk >> 4;
    int b = bt / T_, t = bt % T_;
    int v = threadIdx.x;
    size_t idx = (size_t)bt * D_ + h * 128 + v;
    float l = lm[((size_t)(b * H_ + h)) * T_ + t];
    float o = l * of[idx] + (1.f - l) * os[idx];
    float s = o * o;
    #pragma unroll
    for (int off = 32; off > 0; off >>= 1) s += __shfl_xor(s, off);
    __shared__ float ws2[2];
    if ((threadIdx.x & 63) == 0) ws2[threadIdx.x >> 6] = s;
    __syncthreads();
    float tot = ws2[0] + ws2[1];
    float rms = sqrtf(tot / 128.f + 1e-5f);
    float g = graw[idx] + g2b[h * 128 + v];
    ocb[idx] = f2bf(o / rms * onw[v] * sigmoidf_(g));
}

extern "C" void kernel_launch(void* const* d_in, const int* in_sizes, int n_in,
                              void* d_out, int out_size, void* d_ws, size_t ws_size,
                              hipStream_t stream)
{
    const float* x        = (const float*)d_in[0];
    const float* wq       = (const float*)d_in[1];
    const float* wk       = (const float*)d_in[2];
    const float* wv       = (const float*)d_in[3];
    const float* conv_q_w = (const float*)d_in[4];
    const float* conv_k_w = (const float*)d_in[5];
    const float* conv_v_w = (const float*)d_in[6];
    const float* A_log    = (const float*)d_in[7];
    const float* dt_bias  = (const float*)d_in[8];
    const float* proxy_w  = (const float*)d_in[9];
    const float* unc_w    = (const float*)d_in[10];
    const float* he       = (const float*)d_in[11];
    const float* mlp_w1   = (const float*)d_in[12];
    const float* mlp_b1   = (const float*)d_in[13];
    const float* mlp_w2   = (const float*)d_in[14];
    const float* mlp_b2   = (const float*)d_in[15];
    const float* bb_w     = (const float*)d_in[16];
    const float* bb_b     = (const float*)d_in[17];
    const float* bd_w     = (const float*)d_in[18];
    const float* bd_b     = (const float*)d_in[19];
    const float* lam_w    = (const float*)d_in[20];
    const float* lam_b    = (const float*)d_in[21];
    const float* ab_w     = (const float*)d_in[22];
    const float* ab_b     = (const float*)d_in[23];
    const float* ad_w     = (const float*)d_in[24];
    const float* ad_b     = (const float*)d_in[25];
    const float* g1_w     = (const float*)d_in[26];
    const float* g2_w     = (const float*)d_in[27];
    const float* g2_b     = (const float*)d_in[28];
    const float* onorm_w  = (const float*)d_in[29];
    const float* wo       = (const float*)d_in[30];
    float* out = (float*)d_out;

    float* ws = (float*)d_ws;
    const size_t SZ = (size_t)BT_ * D_;              // 1,048,576
    float* C_big = ws;                               // 512*6336 = 3,244,032
    float* qc    = C_big + (size_t)512 * 6336;
    float* kc    = qc + SZ;
    float* vc    = kc + SZ;
    float* graw  = vc + SZ;
    float* lm    = graw + SZ;                        // 8192
    float* gchan = lm + 8192;                        // 2048
    float* scal4 = gchan + 2048;                     // 65,536
    float* kuA   = scal4 + 65536;                    // 32*256*128 = 1,048,576
    float* dA    = kuA + 1048576;                    // 64*256*128 = 2,097,152
    float* vhatA = dA + 2097152;                     // 1,048,576
    float* fend  = vhatA + 1048576;
    ushort_t* xb = (ushort_t*)fend;                  // 1,048,576 bf16

    // overlays (all lifetimes verified):
    float* o_fast  = kc;                             // kc dead after featsprec
    float* o_slow  = vhatA;                          // vhatA dead after featsprec
    ushort_t* ocb  = xb;                             // xb dead after gemm_proj
    ushort_t* kcb  = (ushort_t*)dA;                  // dA written in featsprec (after vhat GEMM)

    dim3 blk256(256);
    dim3 blk512(512);
    const float QSCALE = 0.08838834764831845f;       // DK^-0.5

    // 1. x -> bf16 (+ gchan precompute, fused)
    cvt_gchan<<<dim3(1032), blk256, 0, stream>>>(x, xb, (int)SZ, A_log, dt_bias, gchan);
    // 2. fused projections: [512][6336] = xb @ [wq|wk|wv|unc|g1]  (256-row tiles)
    gemm_proj<<<dim3(99, 2), blk512, 0, stream>>>(xb, wq, wk, wv, unc_w, g1_w, C_big);
    // 3. conv + silu (q pre-scaled); kc also emitted as bf16
    conv_fused<<<dim3(24, BT_), blk256, 0, stream>>>(C_big, conv_q_w, conv_k_w, conv_v_w,
                                                     qc, kc, vc, kcb, QSCALE);
    // 4. vhat = kcb[8192,128] @ proxy[128,128]  (MFMA)
    gemm_one<<<dim3(2, 128), blk256, 0, stream>>>(kcb, proxy_w, vhatA, 128, 128);
    // 5. fused feats + MLP + scan-operand precompute
    featsprec_k<<<dim3(BT_ * H_), dim3(128), 0, stream>>>(
        kc, vc, qc, vhatA, C_big, he, gchan,
        mlp_w1, mlp_b1, mlp_w2, mlp_b2,
        bb_w, bb_b, bd_w, bd_b, lam_w, lam_b, ab_w, ab_b, ad_w, ad_b,
        lm, kuA, dA, (float4*)scal4);
    // 6. delta-rule scan v-split x8 (blocks 0..511, 2/CU) + g2 GEMM (512..767)
    delta_g2_fused<<<dim3(768), blk256, 0, stream>>>(qc, vc, kuA, dA,
                                                     (const float4*)scal4,
                                                     o_fast, o_slow,
                                                     C_big, g2_w, graw);
    // 7. combine + rmsnorm + gate -> bf16
    combine_k<<<dim3(BT_ * H_), dim3(128), 0, stream>>>(o_fast, o_slow, lm, graw,
                                                        g2_b, onorm_w, ocb);
    // 8. output projection (64-row tiles, full-machine grid)
    gemm_one<<<dim3(32, 8), blk256, 0, stream>>>(ocb, wo, out, 2048, 2048);
}

// Round 21
// 206.325 us; speedup vs baseline: 1.0992x; 1.0992x over previous
//
#include <hip/hip_runtime.h>
#include <hip/hip_bf16.h>
#include <math.h>

#define H_ 16
#define DK_ 128
#define DV_ 128
#define D_ 2048
#define T_ 256
#define B_ 2
#define BT_ 512

typedef __attribute__((ext_vector_type(8))) short short8v;
typedef __attribute__((ext_vector_type(4))) float float4v;
typedef unsigned short ushort_t;

__device__ __forceinline__ float sigmoidf_(float x){ return 1.f/(1.f+expf(-x)); }
__device__ __forceinline__ float siluf_(float x){ return x/(1.f+expf(-x)); }
__device__ __forceinline__ ushort_t f2bf(float f){
    __hip_bfloat16 h = __float2bfloat16(f);
    return *reinterpret_cast<ushort_t*>(&h);
}
// swizzled LDS index (shorts) for N-row x 32-col bf16 tiles; k multiple of 8 in use
__device__ __forceinline__ int swz(int row, int k){
    return row * 32 + ((((k >> 3) ^ (row & 3)) << 3) | (k & 7));
}

// DPP row-rotation sum over a 16-lane row (pure VALU, no LDS pipe).
template<int CTRL>
__device__ __forceinline__ float ror_add_(float x){
    return x + __int_as_float(__builtin_amdgcn_update_dpp(
        0, __float_as_int(x), CTRL, 0xF, 0xF, true));
}
__device__ __forceinline__ float rsum16_(float x){
    x = ror_add_<0x121>(x);
    x = ror_add_<0x122>(x);
    x = ror_add_<0x124>(x);
    x = ror_add_<0x128>(x);
    return x;
}

// ---------------- fused fp32->bf16 + gchan precompute ----------------
__global__ void cvt_gchan(const float* __restrict__ in, ushort_t* __restrict__ out, int n,
                          const float* __restrict__ A_log, const float* __restrict__ dt_bias,
                          float* __restrict__ gchan)
{
    int bid = blockIdx.x;
    if (bid < 1024) {
        int i = (bid * 256 + threadIdx.x) * 4;
        if (i >= n) return;
        float4 v = *(const float4*)&in[i];
        union { ushort_t s[4]; unsigned long long u; } p;
        p.s[0] = f2bf(v.x); p.s[1] = f2bf(v.y); p.s[2] = f2bf(v.z); p.s[3] = f2bf(v.w);
        *(unsigned long long*)&out[i] = p.u;
    } else {
        int i = (bid - 1024) * 256 + threadIdx.x;   // 0..2047
        int h = i >> 7;
        float x = dt_bias[i];
        float sp = (x > 20.f) ? x : log1pf(expf(x));
        gchan[i] = -expf(A_log[h]) * sp * 1.44269504088896f;
    }
}

// ---------------- GEMM core (64-row tiles, 256 thr): proven, for small GEMMs -------
__device__ __forceinline__ void gemm_core(
    const ushort_t* __restrict__ A, int K,
    const float* __restrict__ W, int Nst, int nloc0,
    float* __restrict__ C, int Cst, int m0, int n0out)
{
    __shared__ ushort_t Asub[2048];
    __shared__ ushort_t Bsub[2048];
    const int tid = threadIdx.x;
    const int wid = tid >> 6, lane = tid & 63;
    const int wr = (wid >> 1) * 32, wc = (wid & 1) * 32;
    const int lr = lane & 15, lk = (lane >> 4) * 8;
    const int rowA = tid >> 2, kqA = tid & 3;
    const int nW = tid & 63, kqW = tid >> 6;

    float4v acc[2][2];
    #pragma unroll
    for (int i = 0; i < 2; ++i)
        #pragma unroll
        for (int j = 0; j < 2; ++j) acc[i][j] = (float4v){0.f, 0.f, 0.f, 0.f};

    short8v aRa, aRb;
    float wRa[8], wRb[8];

#define LOADT(AR, WR, KOFF) do {                                                   \
    AR = *(const short8v*)&A[(size_t)(m0 + rowA) * K + (KOFF) + kqA * 8];          \
    _Pragma("unroll")                                                              \
    for (int r = 0; r < 8; ++r)                                                    \
        WR[r] = W[(size_t)((KOFF) + kqW * 8 + r) * Nst + nloc0 + nW];              \
} while (0)
#define STORET(AR, WR) do {                                                        \
    *(short8v*)&Asub[swz(rowA, kqA * 8)] = AR;                                     \
    union { ushort_t s[8]; short8v v; } pk;                                        \
    _Pragma("unroll")                                                              \
    for (int r = 0; r < 8; ++r) pk.s[r] = f2bf(WR[r]);                             \
    *(short8v*)&Bsub[swz(nW, kqW * 8)] = pk.v;                                     \
} while (0)
#define FRAGMMA() do {                                                             \
    short8v af0 = *(const short8v*)&Asub[swz(wr + lr, lk)];                        \
    short8v af1 = *(const short8v*)&Asub[swz(wr + 16 + lr, lk)];                   \
    short8v bf0 = *(const short8v*)&Bsub[swz(wc + lr, lk)];                        \
    short8v bf1 = *(const short8v*)&Bsub[swz(wc + 16 + lr, lk)];                   \
    acc[0][0] = __builtin_amdgcn_mfma_f32_16x16x32_bf16(af0, bf0, acc[0][0],0,0,0);\
    acc[0][1] = __builtin_amdgcn_mfma_f32_16x16x32_bf16(af0, bf1, acc[0][1],0,0,0);\
    acc[1][0] = __builtin_amdgcn_mfma_f32_16x16x32_bf16(af1, bf0, acc[1][0],0,0,0);\
    acc[1][1] = __builtin_amdgcn_mfma_f32_16x16x32_bf16(af1, bf1, acc[1][1],0,0,0);\
} while (0)

    LOADT(aRa, wRa, 0);
    for (int k0 = 0; k0 < K; k0 += 64) {
        STORET(aRa, wRa);
        __syncthreads();
        if (k0 + 32 < K) LOADT(aRb, wRb, k0 + 32);
        FRAGMMA();
        __syncthreads();
        STORET(aRb, wRb);
        __syncthreads();
        if (k0 + 64 < K) LOADT(aRa, wRa, k0 + 64);
        FRAGMMA();
        __syncthreads();
    }
#undef LOADT
#undef STORET
#undef FRAGMMA
    const int lq = (lane >> 4) * 4;
    #pragma unroll
    for (int mi = 0; mi < 2; ++mi)
        #pragma unroll
        for (int ni = 0; ni < 2; ++ni)
            #pragma unroll
            for (int j = 0; j < 4; ++j)
                C[(size_t)(m0 + wr + mi * 16 + lq + j) * Cst + (n0out + wc + ni * 16 + lr)]
                    = acc[mi][ni][j];
}

// ---------------- GEMM core2 (256-row tiles, 512 thr) ----------
__device__ __forceinline__ void gemm_core2(
    const ushort_t* __restrict__ A, int K,
    const float* __restrict__ W, int Nst, int nloc0,
    float* __restrict__ C, int Cst, int m0, int n0out)
{
    __shared__ ushort_t Asub[8192];   // 256 x 32, swizzled
    __shared__ ushort_t Bsub[2048];   // 64 x 32, swizzled
    const int tid = threadIdx.x;      // 0..511
    const int wid = tid >> 6, lane = tid & 63;
    const int wr = wid * 32;
    const int lr = lane & 15, lk = (lane >> 4) * 8;
    const int rowA = tid >> 2;
    const int kqA  = (tid & 3) * 8;
    const int nW = tid & 63, kqW = (tid >> 6) & 3;
    const bool doW = tid < 256;

    float4v acc[2][4];
    #pragma unroll
    for (int i = 0; i < 2; ++i)
        #pragma unroll
        for (int j = 0; j < 4; ++j) acc[i][j] = (float4v){0.f, 0.f, 0.f, 0.f};

    short8v a0a, a1a, a0b, a1b;
    float wRa[8], wRb[8];

#define LOADT2(A0, A1, WR, KOFF) do {                                              \
    A0 = *(const short8v*)&A[(size_t)(m0 + rowA) * K + (KOFF) + kqA];              \
    A1 = *(const short8v*)&A[(size_t)(m0 + rowA + 128) * K + (KOFF) + kqA];        \
    if (doW) {                                                                     \
        _Pragma("unroll")                                                          \
        for (int r = 0; r < 8; ++r)                                                \
            WR[r] = W[(size_t)((KOFF) + kqW * 8 + r) * Nst + nloc0 + nW];          \
    }                                                                              \
} while (0)
#define STORET2(A0, A1, WR) do {                                                   \
    *(short8v*)&Asub[swz(rowA, kqA)] = A0;                                         \
    *(short8v*)&Asub[swz(rowA + 128, kqA)] = A1;                                   \
    if (doW) {                                                                     \
        union { ushort_t s[8]; short8v v; } pk;                                    \
        _Pragma("unroll")                                                          \
        for (int r = 0; r < 8; ++r) pk.s[r] = f2bf(WR[r]);                         \
        *(short8v*)&Bsub[swz(nW, kqW * 8)] = pk.v;                                 \
    }                                                                              \
} while (0)
#define FRAGMMA2() do {                                                            \
    short8v af0 = *(const short8v*)&Asub[swz(wr + lr, lk)];                        \
    short8v af1 = *(const short8v*)&Asub[swz(wr + 16 + lr, lk)];                   \
    short8v bf0 = *(const short8v*)&Bsub[swz(lr, lk)];                             \
    short8v bf1 = *(const short8v*)&Bsub[swz(16 + lr, lk)];                        \
    short8v bf2 = *(const short8v*)&Bsub[swz(32 + lr, lk)];                        \
    short8v bf3 = *(const short8v*)&Bsub[swz(48 + lr, lk)];                        \
    acc[0][0] = __builtin_amdgcn_mfma_f32_16x16x32_bf16(af0, bf0, acc[0][0],0,0,0);\
    acc[0][1] = __builtin_amdgcn_mfma_f32_16x16x32_bf16(af0, bf1, acc[0][1],0,0,0);\
    acc[0][2] = __builtin_amdgcn_mfma_f32_16x16x32_bf16(af0, bf2, acc[0][2],0,0,0);\
    acc[0][3] = __builtin_amdgcn_mfma_f32_16x16x32_bf16(af0, bf3, acc[0][3],0,0,0);\
    acc[1][0] = __builtin_amdgcn_mfma_f32_16x16x32_bf16(af1, bf0, acc[1][0],0,0,0);\
    acc[1][1] = __builtin_amdgcn_mfma_f32_16x16x32_bf16(af1, bf1, acc[1][1],0,0,0);\
    acc[1][2] = __builtin_amdgcn_mfma_f32_16x16x32_bf16(af1, bf2, acc[1][2],0,0,0);\
    acc[1][3] = __builtin_amdgcn_mfma_f32_16x16x32_bf16(af1, bf3, acc[1][3],0,0,0);\
} while (0)

    LOADT2(a0a, a1a, wRa, 0);
    for (int k0 = 0; k0 < K; k0 += 64) {
        STORET2(a0a, a1a, wRa);
        __syncthreads();
        if (k0 + 32 < K) LOADT2(a0b, a1b, wRb, k0 + 32);
        FRAGMMA2();
        __syncthreads();
        STORET2(a0b, a1b, wRb);
        __syncthreads();
        if (k0 + 64 < K) LOADT2(a0a, a1a, wRa, k0 + 64);
        FRAGMMA2();
        __syncthreads();
    }
#undef LOADT2
#undef STORET2
#undef FRAGMMA2
    const int lq = (lane >> 4) * 4;
    #pragma unroll
    for (int mi = 0; mi < 2; ++mi)
        #pragma unroll
        for (int ni = 0; ni < 4; ++ni)
            #pragma unroll
            for (int j = 0; j < 4; ++j)
                C[(size_t)(m0 + wr + mi * 16 + lq + j) * Cst + (n0out + ni * 16 + lr)]
                    = acc[mi][ni][j];
}

// fused projection GEMM: N = 6336 = wq(2048) | wk(2048) | wv(2048) | unc(64) | g1(128)
__global__ __launch_bounds__(512) void gemm_proj(const ushort_t* __restrict__ A,
    const float* __restrict__ wq, const float* __restrict__ wk, const float* __restrict__ wv,
    const float* __restrict__ unc, const float* __restrict__ g1, float* __restrict__ C)
{
    int n0 = blockIdx.x * 64, m0 = blockIdx.y * 256;
    const float* W; int nloc, Nst;
    if (n0 < 2048)      { W = wq;  nloc = n0;        Nst = 2048; }
    else if (n0 < 4096) { W = wk;  nloc = n0 - 2048; Nst = 2048; }
    else if (n0 < 6144) { W = wv;  nloc = n0 - 4096; Nst = 2048; }
    else if (n0 < 6208) { W = unc; nloc = n0 - 6144; Nst = 64; }
    else                { W = g1;  nloc = n0 - 6208; Nst = 128; }
    gemm_core2(A, 2048, W, Nst, nloc, C, 6336, m0, n0);
}

// single-weight GEMM (64-tile): C[M,N] = A[M,K] @ W[K,N]
__global__ __launch_bounds__(256) void gemm_one(const ushort_t* __restrict__ A,
    const float* __restrict__ W, float* __restrict__ C, int N, int K)
{
    gemm_core(A, K, W, N, blockIdx.x * 64, C, N, blockIdx.y * 64, blockIdx.x * 64);
}

// ---------------- fused causal depthwise conv (K=4) + SiLU over q|k|v --------------
__global__ void conv_fused(const float* __restrict__ Cb,
    const float* __restrict__ wq, const float* __restrict__ wk, const float* __restrict__ wv,
    float* __restrict__ qc, float* __restrict__ kc, float* __restrict__ vc,
    ushort_t* __restrict__ kcb, float qscale)
{
    int c  = blockIdx.x * 256 + threadIdx.x;   // 0..6143
    int bt = blockIdx.y;
    int b  = bt / T_, t = bt % T_;
    int which = c >> 11, cloc = c & 2047;
    const float* w = which == 0 ? wq : which == 1 ? wk : wv;
    float* o = which == 0 ? qc : which == 1 ? kc : vc;
    float scale = which == 0 ? qscale : 1.f;
    float acc = 0.f;
    #pragma unroll
    for (int j = 0; j < 4; ++j) {
        int tt = t - 3 + j;
        if (tt >= 0) acc = fmaf(w[cloc * 4 + j], Cb[((size_t)(b * T_ + tt)) * 6336 + c], acc);
    }
    float r = siluf_(acc) * scale;
    o[(size_t)bt * D_ + cloc] = r;
    if (which == 1) kcb[(size_t)bt * D_ + cloc] = f2bf(r);
}

// ---------- fused per-(b,t,h) features + MLP + scan-operand precompute -------------
__global__ __launch_bounds__(128) void featsprec_k(
    const float* __restrict__ kc, const float* __restrict__ vc,
    const float* __restrict__ qc,
    const float* __restrict__ vhatA, const float* __restrict__ Cb,
    const float* __restrict__ he, const float* __restrict__ gchan,
    const float* __restrict__ w1, const float* __restrict__ b1,
    const float* __restrict__ w2, const float* __restrict__ b2,
    const float* __restrict__ bbw, const float* __restrict__ bbb,
    const float* __restrict__ bdw, const float* __restrict__ bdb,
    const float* __restrict__ lamw, const float* __restrict__ lamb,
    const float* __restrict__ abw, const float* __restrict__ abb,
    const float* __restrict__ adw, const float* __restrict__ adb,
    float* __restrict__ lm, float* __restrict__ kuA,
    float* __restrict__ dA, float4* __restrict__ scal4A)
{
    int blk = blockIdx.x;          // (b*T+t)*H + h
    int h = blk & 15, bt = blk >> 4;
    int b = bt / T_, t = bt % T_;
    int v = threadIdx.x;           // 0..127
    __shared__ float part[2][5];
    __shared__ float tot5[5];
    __shared__ float feats8[8];
    __shared__ float hf1[32];
    __shared__ float hf[32];
    __shared__ float entSh;
    __shared__ float scal5[5];     // bfv, bsv, afv, asv, knorm

    if (v < 64) {
        float x = Cb[(size_t)bt * 6336 + 6144 + v];
        float m = x;
        #pragma unroll
        for (int o = 32; o > 0; o >>= 1) m = fmaxf(m, __shfl_xor(m, o));
        float e = expf(x - m);
        float s = e;
        #pragma unroll
        for (int o = 32; o > 0; o >>= 1) s += __shfl_xor(s, o);
        float lp = (x - m) - logf(s);
        float c = -expf(lp) * lp;
        #pragma unroll
        for (int o = 32; o > 0; o >>= 1) c += __shfl_xor(c, o);
        if (v == 0) entSh = c / logf(64.f);
    }

    size_t base = (size_t)bt * D_ + h * 128;
    float kval = kc[base + v];
    float vval = vc[base + v];
    float vhat = vhatA[(size_t)blk * 128 + v];

    float e = vval - vhat;
    float sums[5] = {kval * kval, vval * vval, vhat * vhat, vval * vhat, e * e};
    #pragma unroll
    for (int i = 0; i < 5; ++i) {
        float s = sums[i];
        #pragma unroll
        for (int o = 32; o > 0; o >>= 1) s += __shfl_xor(s, o);
        if ((threadIdx.x & 63) == 0) part[threadIdx.x >> 6][i] = s;
    }
    __syncthreads();
    if (threadIdx.x < 5) tot5[threadIdx.x] = part[0][threadIdx.x] + part[1][threadIdx.x];
    __syncthreads();
    if (threadIdx.x == 0) {
        float k2 = tot5[0], v2 = tot5[1], vh2 = tot5[2], vvh = tot5[3], e2 = tot5[4];
        float knorm = sqrtf(k2);
        float err_n = sqrtf(e2);
        float v_n = sqrtf(v2);
        float vh_n = sqrtf(vh2);
        feats8[0] = entSh;
        feats8[1] = err_n / (v_n + 1e-6f);
        feats8[2] = vvh / (v_n * vh_n + 1e-6f);
        feats8[3] = log1pf(err_n);
        feats8[4] = he[h * 4 + 0];
        feats8[5] = he[h * 4 + 1];
        feats8[6] = he[h * 4 + 2];
        feats8[7] = he[h * 4 + 3];
        scal5[4] = knorm;
    }
    __syncthreads();
    if (threadIdx.x < 32) {
        float a = b1[threadIdx.x];
        #pragma unroll
        for (int j = 0; j < 8; ++j) a = fmaf(feats8[j], w1[j * 32 + threadIdx.x], a);
        hf1[threadIdx.x] = siluf_(a);
    }
    __syncthreads();
    if (threadIdx.x < 32) {
        float a = b2[threadIdx.x];
        #pragma unroll
        for (int j = 0; j < 32; ++j) a = fmaf(hf1[j], w2[j * 32 + threadIdx.x], a);
        hf[threadIdx.x] = siluf_(a);
    }
    __syncthreads();
    if (threadIdx.x == 0) {
        float bb = bbb[0], bd = bdb[0], lv = lamb[0], ab = abb[0], ad = adb[0];
        #pragma unroll
        for (int j = 0; j < 32; ++j) {
            float hj = hf[j];
            bb = fmaf(hj, bbw[j], bb);
            bd = fmaf(hj, bdw[j], bd);
            lv = fmaf(hj, lamw[j], lv);
            ab = fmaf(hj, abw[j], ab);
            ad = fmaf(hj, adw[j], ad);
        }
        scal5[0] = sigmoidf_(bb + bd);
        scal5[1] = sigmoidf_(bb - bd);
        scal5[2] = sigmoidf_(ab + ad);
        scal5[3] = sigmoidf_(ab - ad);
        lm[((size_t)(b * H_ + h)) * T_ + t] = sigmoidf_(lv);
    }
    __syncthreads();

    // ---- scan-operand precompute (reads precomputed gchan) ----
    const float bfv = scal5[0], bsv = scal5[1];
    const float afv = scal5[2], asv = scal5[3], knv = scal5[4];
    const int k = threadIdx.x;
    const int bh = b * 16 + h;
    float gch = gchan[h * 128 + k];
    float kuv = kval / (knv + 1e-6f);
    kuA[((size_t)bh * 256 + t) * 128 + k] = kuv;
    dA[((size_t)bh * 256 + t) * 128 + k]        = exp2f(gch * afv);   // rule 0
    dA[((size_t)(32 + bh) * 256 + t) * 128 + k] = exp2f(gch * asv);   // rule 1
    float pq = qc[base + k] * kuv;
    #pragma unroll
    for (int o = 32; o > 0; o >>= 1) pq += __shfl_xor(pq, o);
    if ((threadIdx.x & 63) == 0) part[threadIdx.x >> 6][0] = pq;
    __syncthreads();
    if (threadIdx.x == 0) {
        float pt = part[0][0] + part[1][0];
        float4 s0; s0.x = afv; s0.y = bfv; s0.z = pt * bfv; s0.w = 0.f;
        float4 s1; s1.x = asv; s1.y = bsv; s1.z = pt * bsv; s1.w = 0.f;
        scal4A[(size_t)bh * 256 + t] = s0;
        scal4A[(size_t)(32 + bh) * 256 + t] = s1;
    }
}

// ------ fused delta-rule scan (blocks 0..255) + g2 GEMM (blocks 256..511) ----------
// g2 runs in the scan's occupancy shadow (scan = 4 waves/CU). LDS unioned.
struct OPS { float4 a0, a1, q0, q1, d0, d1; float2 vv, sc2; };

__global__ __launch_bounds__(256) void delta_g2_fused(
    const float* __restrict__ qc, const float* __restrict__ vc,
    const float* __restrict__ kuA, const float* __restrict__ dA,
    const float4* __restrict__ scal4A,
    float* __restrict__ o_fast, float* __restrict__ o_slow,
    const float* __restrict__ Cb, const float* __restrict__ g2w,
    float* __restrict__ graw)
{
    __shared__ __align__(16) char smem[59648];
    const int tid = threadIdx.x;

    if (blockIdx.x >= 256) {
        // ---------------- g2 GEMM path: graw = Cb[:,6208:6336] @ g2w ----------------
        ushort_t* Asub = (ushort_t*)smem;            // 2048 shorts
        ushort_t* Bsub = (ushort_t*)(smem + 4096);   // 2048 shorts
        const int p2 = blockIdx.x - 256;             // 0..255
        const int m0 = (p2 >> 5) * 64, n0 = (p2 & 31) * 64;
        const int wid = tid >> 6, lane = tid & 63;
        const int wr = (wid >> 1) * 32, wc = (wid & 1) * 32;
        const int lr = lane & 15, lk = (lane >> 4) * 8;
        const int rowA = tid >> 2, kqA = (tid & 3) * 8;
        const int nW = tid & 63, kqW = tid >> 6;

        float4v acc[2][2];
        #pragma unroll
        for (int i = 0; i < 2; ++i)
            #pragma unroll
            for (int j = 0; j < 2; ++j) acc[i][j] = (float4v){0.f, 0.f, 0.f, 0.f};

        for (int k0 = 0; k0 < 128; k0 += 32) {
            const float* asrc = &Cb[(size_t)(m0 + rowA) * 6336 + 6208 + k0 + kqA];
            float4 a4a = *(const float4*)asrc;
            float4 a4b = *(const float4*)(asrc + 4);
            float w8[8];
            #pragma unroll
            for (int r = 0; r < 8; ++r)
                w8[r] = g2w[(size_t)(k0 + kqW * 8 + r) * 2048 + n0 + nW];
            __syncthreads();
            union { ushort_t s[8]; short8v v; } pa, pw;
            pa.s[0]=f2bf(a4a.x); pa.s[1]=f2bf(a4a.y); pa.s[2]=f2bf(a4a.z); pa.s[3]=f2bf(a4a.w);
            pa.s[4]=f2bf(a4b.x); pa.s[5]=f2bf(a4b.y); pa.s[6]=f2bf(a4b.z); pa.s[7]=f2bf(a4b.w);
            *(short8v*)&Asub[swz(rowA, kqA)] = pa.v;
            #pragma unroll
            for (int r = 0; r < 8; ++r) pw.s[r] = f2bf(w8[r]);
            *(short8v*)&Bsub[swz(nW, kqW * 8)] = pw.v;
            __syncthreads();
            short8v af0 = *(const short8v*)&Asub[swz(wr + lr, lk)];
            short8v af1 = *(const short8v*)&Asub[swz(wr + 16 + lr, lk)];
            short8v bf0 = *(const short8v*)&Bsub[swz(wc + lr, lk)];
            short8v bf1 = *(const short8v*)&Bsub[swz(wc + 16 + lr, lk)];
            acc[0][0] = __builtin_amdgcn_mfma_f32_16x16x32_bf16(af0, bf0, acc[0][0],0,0,0);
            acc[0][1] = __builtin_amdgcn_mfma_f32_16x16x32_bf16(af0, bf1, acc[0][1],0,0,0);
            acc[1][0] = __builtin_amdgcn_mfma_f32_16x16x32_bf16(af1, bf0, acc[1][0],0,0,0);
            acc[1][1] = __builtin_amdgcn_mfma_f32_16x16x32_bf16(af1, bf1, acc[1][1],0,0,0);
        }
        const int lq = (lane >> 4) * 4;
        #pragma unroll
        for (int mi = 0; mi < 2; ++mi)
            #pragma unroll
            for (int ni = 0; ni < 2; ++ni)
                #pragma unroll
                for (int j = 0; j < 4; ++j)
                    graw[(size_t)(m0 + wr + mi * 16 + lq + j) * 2048 + (n0 + wc + ni * 16 + lr)]
                        = acc[mi][ni][j];
        return;
    }

    // ---------------- scan path (identical structure to delta_wave9) ----------------
    float (*kuL)[16][144] = (float (*)[16][144])(smem);            // 18432 B
    float (*qL)[16][144]  = (float (*)[16][144])(smem + 18432);    // 18432 B
    float (*dL)[16][144]  = (float (*)[16][144])(smem + 36864);    // 18432 B
    float (*vL)[16][32]   = (float (*)[16][32])(smem + 55296);     //  4096 B
    float (*scL)[16][2]   = (float (*)[16][2])(smem + 59392);      //   256 B

    const int p  = blockIdx.x;                    // 0..255 ; XCD = p & 7
    const int lb = (p & 7) * 32 + (p >> 3);       // bh*8 + rule*4 + vq
    const int bh = lb >> 3, rule = (lb >> 2) & 1, vq = lb & 3;
    const int b = bh >> 4, h = bh & 15;
    const int rbh = rule * 32 + bh;
    const int wid = tid >> 6, lane = tid & 63;
    const int kl = lane & 15, vg = lane >> 4;
    const int vloc = wid * 8 + vg * 2;            // 0..30 within 32-col slice
    const int vcol = vq * 32 + vloc;

    const float*  __restrict__ pkuG = kuA + (size_t)bh * 256 * 128;
    const float*  __restrict__ pdG  = dA + (size_t)rbh * 256 * 128;
    const float*  __restrict__ pqG  = qc + (size_t)b * T_ * D_ + h * 128;
    const float*  __restrict__ pvG  = vc + (size_t)b * T_ * D_ + h * 128 + vq * 32;
    const float4* __restrict__ pscG = scal4A + (size_t)rbh * 256;
    float* __restrict__ obase = (rule ? o_slow : o_fast)
                                + (size_t)b * T_ * D_ + h * 128 + vcol;

    const int srow = (tid & 127) >> 3;            // 0..15
    const int scol = (tid & 7) * 16;              // 0..112
    const bool isK = tid < 128;
    const int ck0 = scol >> 3;                    // 8-float group index (even)
    const int fo_w0 = ck0 * 8 + (ck0 >> 2) * 4;
    const int fo_w1 = (ck0 + 1) * 8 + ((ck0 + 1) >> 2) * 4;

    float4 sb0, sb1, sb2, sb3, svb, ssc, sd0, sd1;

    float S[8][2];
    #pragma unroll
    for (int j = 0; j < 8; ++j) { S[j][0] = 0.f; S[j][1] = 0.f; }

#define STAGE_LOAD(C) do {                                                         \
    const int t0_ = (C) * 16;                                                      \
    const float* dsrc = pdG + (size_t)(t0_ + srow) * 128 + scol;                   \
    if (isK) {                                                                     \
        const float* src = pkuG + (size_t)(t0_ + srow) * 128 + scol;               \
        sb0 = *(const float4*)(src);      sb1 = *(const float4*)(src + 4);         \
        sb2 = *(const float4*)(src + 8);  sb3 = *(const float4*)(src + 12);        \
        svb = *(const float4*)(pvG + (size_t)(t0_ + srow) * D_ + (tid & 7) * 4);   \
        sd0 = *(const float4*)(dsrc);     sd1 = *(const float4*)(dsrc + 4);        \
    } else {                                                                       \
        const float* src = pqG + (size_t)(t0_ + srow) * D_ + scol;                 \
        sb0 = *(const float4*)(src);      sb1 = *(const float4*)(src + 4);         \
        sb2 = *(const float4*)(src + 8);  sb3 = *(const float4*)(src + 12);        \
        sd0 = *(const float4*)(dsrc + 8); sd1 = *(const float4*)(dsrc + 12);       \
        if ((tid & 127) < 16) ssc = *(const float4*)&pscG[t0_ + (tid & 127)];      \
    }                                                                              \
} while (0)

#define STAGE_WRITE(BI) do {                                                       \
    if (isK) {                                                                     \
        *(float4*)&kuL[BI][srow][fo_w0]     = sb0;                                 \
        *(float4*)&kuL[BI][srow][fo_w0 + 4] = sb1;                                 \
        *(float4*)&kuL[BI][srow][fo_w1]     = sb2;                                 \
        *(float4*)&kuL[BI][srow][fo_w1 + 4] = sb3;                                 \
        *(float4*)&vL[BI][srow][(tid & 7) * 4] = svb;                              \
        *(float4*)&dL[BI][srow][fo_w0]      = sd0;                                 \
        *(float4*)&dL[BI][srow][fo_w0 + 4]  = sd1;                                 \
    } else {                                                                       \
        *(float4*)&qL[BI][srow][fo_w0]     = sb0;                                  \
        *(float4*)&qL[BI][srow][fo_w0 + 4] = sb1;                                  \
        *(float4*)&qL[BI][srow][fo_w1]     = sb2;                                  \
        *(float4*)&qL[BI][srow][fo_w1 + 4] = sb3;                                  \
        *(float4*)&dL[BI][srow][fo_w1]      = sd0;                                 \
        *(float4*)&dL[BI][srow][fo_w1 + 4]  = sd1;                                 \
        if ((tid & 127) < 16) {                                                    \
            float2 w2_; w2_.x = ssc.y; w2_.y = ssc.z;                              \
            *(float2*)&scL[BI][tid & 127][0] = w2_;                                \
        }                                                                          \
    }                                                                              \
} while (0)

#define LDOPS(R, BI, TS) do {                                                      \
    R.a0 = *(const float4*)&kuL[BI][TS][fo];                                       \
    R.a1 = *(const float4*)&kuL[BI][TS][fo + 4];                                   \
    R.q0 = *(const float4*)&qL[BI][TS][fo];                                        \
    R.q1 = *(const float4*)&qL[BI][TS][fo + 4];                                    \
    R.d0 = *(const float4*)&dL[BI][TS][fo];                                        \
    R.d1 = *(const float4*)&dL[BI][TS][fo + 4];                                    \
    R.vv = *(const float2*)&vL[BI][TS][vloc];                                      \
    R.sc2 = *(const float2*)&scL[BI][TS][0];                                       \
} while (0)

#define STEP(TT, CUR, NXT, BI) do {                                                \
    if ((TT) + 1 < 16) LDOPS(NXT, BI, (TT) + 1);                                   \
    float ku[8] = {CUR.a0.x, CUR.a0.y, CUR.a0.z, CUR.a0.w,                         \
                   CUR.a1.x, CUR.a1.y, CUR.a1.z, CUR.a1.w};                        \
    float qv[8] = {CUR.q0.x, CUR.q0.y, CUR.q0.z, CUR.q0.w,                         \
                   CUR.q1.x, CUR.q1.y, CUR.q1.z, CUR.q1.w};                        \
    float d[8]  = {CUR.d0.x, CUR.d0.y, CUR.d0.z, CUR.d0.w,                         \
                   CUR.d1.x, CUR.d1.y, CUR.d1.z, CUR.d1.w};                        \
    float vp0a = 0.f, vp0b = 0.f, vp1a = 0.f, vp1b = 0.f;                          \
    float oq0a = 0.f, oq0b = 0.f, oq1a = 0.f, oq1b = 0.f;                          \
    _Pragma("unroll")                                                              \
    for (int j = 0; j < 4; ++j) {                                                  \
        float kudA = ku[j] * d[j],     qdA = qv[j] * d[j];                         \
        float kudB = ku[j+4] * d[j+4], qdB = qv[j+4] * d[j+4];                     \
        vp0a = fmaf(kudA, S[j][0], vp0a);   vp0b = fmaf(kudB, S[j+4][0], vp0b);    \
        vp1a = fmaf(kudA, S[j][1], vp1a);   vp1b = fmaf(kudB, S[j+4][1], vp1b);    \
        oq0a = fmaf(qdA,  S[j][0], oq0a);   oq0b = fmaf(qdB,  S[j+4][0], oq0b);    \
        oq1a = fmaf(qdA,  S[j][1], oq1a);   oq1b = fmaf(qdB,  S[j+4][1], oq1b);    \
    }                                                                              \
    float vp0 = rsum16_(vp0a + vp0b);                                              \
    float vp1 = rsum16_(vp1a + vp1b);                                              \
    float oq0 = rsum16_(oq0a + oq0b);                                              \
    float oq1 = rsum16_(oq1a + oq1b);                                              \
    float dv0 = CUR.vv.x - vp0, dv1 = CUR.vv.y - vp1;                              \
    float o0 = fmaf(CUR.sc2.y, dv0, oq0);                                          \
    float o1 = fmaf(CUR.sc2.y, dv1, oq1);                                          \
    float bd0 = CUR.sc2.x * dv0, bd1 = CUR.sc2.x * dv1;                            \
    _Pragma("unroll")                                                              \
    for (int j = 0; j < 8; ++j) {                                                  \
        S[j][0] = fmaf(d[j], S[j][0], ku[j] * bd0);                                \
        S[j][1] = fmaf(d[j], S[j][1], ku[j] * bd1);                                \
    }                                                                              \
    if (kl == 0) {                                                                 \
        float2 ov; ov.x = o0; ov.y = o1;                                           \
        *(float2*)&obase[(size_t)(tb + (TT)) * D_] = ov;                           \
    }                                                                              \
} while (0)

    const int fo = kl * 8 + (kl >> 2) * 4;

    STAGE_LOAD(0);
    STAGE_WRITE(0);
    __syncthreads();

    OPS rA, rB;
    for (int c = 0; c < 16; ++c) {
        if (c < 15) STAGE_LOAD(c + 1);
        const int bi = c & 1;
        const int tb = c * 16;
        LDOPS(rA, bi, 0);
        #pragma unroll
        for (int ts = 0; ts < 16; ts += 2) {
            STEP(ts,     rA, rB, bi);
            STEP(ts + 1, rB, rA, bi);
        }
        if (c < 15) STAGE_WRITE((c + 1) & 1);
        __syncthreads();
    }
#undef STAGE_LOAD
#undef STAGE_WRITE
#undef LDOPS
#undef STEP
}

// ---------------- combine fast/slow + RMSNorm + sigmoid gate -> bf16 ----------------
__global__ __launch_bounds__(128) void combine_k(
    const float* __restrict__ of, const float* __restrict__ os,
    const float* __restrict__ lm, const float* __restrict__ graw,
    const float* __restrict__ g2b, const float* __restrict__ onw,
    ushort_t* __restrict__ ocb)
{
    int blk = blockIdx.x;          // (b*T+t)*H + h
    int h = blk & 15, bt = blk >> 4;
    int b = bt / T_, t = bt % T_;
    int v = threadIdx.x;
    size_t idx = (size_t)bt * D_ + h * 128 + v;
    float l = lm[((size_t)(b * H_ + h)) * T_ + t];
    float o = l * of[idx] + (1.f - l) * os[idx];
    float s = o * o;
    #pragma unroll
    for (int off = 32; off > 0; off >>= 1) s += __shfl_xor(s, off);
    __shared__ float ws2[2];
    if ((threadIdx.x & 63) == 0) ws2[threadIdx.x >> 6] = s;
    __syncthreads();
    float tot = ws2[0] + ws2[1];
    float rms = sqrtf(tot / 128.f + 1e-5f);
    float g = graw[idx] + g2b[h * 128 + v];
    ocb[idx] = f2bf(o / rms * onw[v] * sigmoidf_(g));
}

extern "C" void kernel_launch(void* const* d_in, const int* in_sizes, int n_in,
                              void* d_out, int out_size, void* d_ws, size_t ws_size,
                              hipStream_t stream)
{
    const float* x        = (const float*)d_in[0];
    const float* wq       = (const float*)d_in[1];
    const float* wk       = (const float*)d_in[2];
    const float* wv       = (const float*)d_in[3];
    const float* conv_q_w = (const float*)d_in[4];
    const float* conv_k_w = (const float*)d_in[5];
    const float* conv_v_w = (const float*)d_in[6];
    const float* A_log    = (const float*)d_in[7];
    const float* dt_bias  = (const float*)d_in[8];
    const float* proxy_w  = (const float*)d_in[9];
    const float* unc_w    = (const float*)d_in[10];
    const float* he       = (const float*)d_in[11];
    const float* mlp_w1   = (const float*)d_in[12];
    const float* mlp_b1   = (const float*)d_in[13];
    const float* mlp_w2   = (const float*)d_in[14];
    const float* mlp_b2   = (const float*)d_in[15];
    const float* bb_w     = (const float*)d_in[16];
    const float* bb_b     = (const float*)d_in[17];
    const float* bd_w     = (const float*)d_in[18];
    const float* bd_b     = (const float*)d_in[19];
    const float* lam_w    = (const float*)d_in[20];
    const float* lam_b    = (const float*)d_in[21];
    const float* ab_w     = (const float*)d_in[22];
    const float* ab_b     = (const float*)d_in[23];
    const float* ad_w     = (const float*)d_in[24];
    const float* ad_b     = (const float*)d_in[25];
    const float* g1_w     = (const float*)d_in[26];
    const float* g2_w     = (const float*)d_in[27];
    const float* g2_b     = (const float*)d_in[28];
    const float* onorm_w  = (const float*)d_in[29];
    const float* wo       = (const float*)d_in[30];
    float* out = (float*)d_out;

    float* ws = (float*)d_ws;
    const size_t SZ = (size_t)BT_ * D_;              // 1,048,576
    float* C_big = ws;                               // 512*6336 = 3,244,032
    float* qc    = C_big + (size_t)512 * 6336;
    float* kc    = qc + SZ;
    float* vc    = kc + SZ;
    float* graw  = vc + SZ;
    float* lm    = graw + SZ;                        // 8192
    float* gchan = lm + 8192;                        // 2048
    float* scal4 = gchan + 2048;                     // 65,536
    float* kuA   = scal4 + 65536;                    // 32*256*128 = 1,048,576
    float* dA    = kuA + 1048576;                    // 64*256*128 = 2,097,152
    float* vhatA = dA + 2097152;                     // 1,048,576
    float* fend  = vhatA + 1048576;
    ushort_t* xb = (ushort_t*)fend;                  // 1,048,576 bf16

    // overlays (all lifetimes verified):
    float* o_fast  = kc;                             // kc dead after featsprec
    float* o_slow  = vhatA;                          // vhatA dead after featsprec
    ushort_t* ocb  = xb;                             // xb dead after gemm_proj
    ushort_t* kcb  = (ushort_t*)dA;                  // dA written in featsprec (after vhat GEMM)

    dim3 blk256(256);
    dim3 blk512(512);
    const float QSCALE = 0.08838834764831845f;       // DK^-0.5

    // 1. x -> bf16 (+ gchan precompute, fused)
    cvt_gchan<<<dim3(1032), blk256, 0, stream>>>(x, xb, (int)SZ, A_log, dt_bias, gchan);
    // 2. fused projections: [512][6336] = xb @ [wq|wk|wv|unc|g1]  (256-row tiles)
    gemm_proj<<<dim3(99, 2), blk512, 0, stream>>>(xb, wq, wk, wv, unc_w, g1_w, C_big);
    // 3. conv + silu (q pre-scaled); kc also emitted as bf16
    conv_fused<<<dim3(24, BT_), blk256, 0, stream>>>(C_big, conv_q_w, conv_k_w, conv_v_w,
                                                     qc, kc, vc, kcb, QSCALE);
    // 4. vhat = kcb[8192,128] @ proxy[128,128]  (MFMA)
    gemm_one<<<dim3(2, 128), blk256, 0, stream>>>(kcb, proxy_w, vhatA, 128, 128);
    // 5. fused feats + MLP + scan-operand precompute
    featsprec_k<<<dim3(BT_ * H_), dim3(128), 0, stream>>>(
        kc, vc, qc, vhatA, C_big, he, gchan,
        mlp_w1, mlp_b1, mlp_w2, mlp_b2,
        bb_w, bb_b, bd_w, bd_b, lam_w, lam_b, ab_w, ab_b, ad_w, ad_b,
        lm, kuA, dA, (float4*)scal4);
    // 6. delta-rule scan (blocks 0..255) + g2 GEMM (blocks 256..511, runs in shadow)
    delta_g2_fused<<<dim3(512), blk256, 0, stream>>>(qc, vc, kuA, dA,
                                                     (const float4*)scal4,
                                                     o_fast, o_slow,
                                                     C_big, g2_w, graw);
    // 7. combine + rmsnorm + gate -> bf16
    combine_k<<<dim3(BT_ * H_), dim3(128), 0, stream>>>(o_fast, o_slow, lm, graw,
                                                        g2_b, onorm_w, ocb);
    // 8. output projection (64-row tiles, full-machine grid)
    gemm_one<<<dim3(32, 8), blk256, 0, stream>>>(ocb, wo, out, 2048, 2048);
}